// Round 7
// baseline (139.663 us; speedup 1.0000x reference)
//
#include <hip/hip_runtime.h>

#define HID 128
#define NODE_PAD 50048   // padded node count (multiple of 16; covers 50000)
#define NRANGE 4         // node ranges (LDS histogram per range)
#define RANGE 12512      // NODE_PAD / NRANGE  (48.9 KB of LDS bins)
#define NPART 64         // edge chunks = partial aggregate buffers
#define NGRP 4           // reduced partial groups read by the MLP

typedef __attribute__((ext_vector_type(8))) short short8;   // bf16x8 A/B frag (4 VGPRs)
typedef __attribute__((ext_vector_type(4))) float floatx4;  // C/D frag

// fp32 -> bf16 (RNE) as raw short
__device__ __forceinline__ short f2bf(float f) {
    unsigned u = __builtin_bit_cast(unsigned, f);
    unsigned r = (u + 0x7FFFu + ((u >> 16) & 1u)) >> 16;
    return (short)r;
}

// ---------------------------------------------------------------------------
// Kernel 1: scatter-add with ZERO global atomics (round-3 lesson: device
// fp32 atomics bottleneck at ~19 G/s with 32 B write-through each).
// Block (r,b) bins node range r of edge chunk b into LDS, then streams the
// bins to part[b] with plain coalesced stores.
// ---------------------------------------------------------------------------
__global__ __launch_bounds__(256) void scatter_lds(const int* __restrict__ rows,
                                                   const float* __restrict__ dist,
                                                   float* __restrict__ part,
                                                   int n_edges) {
    __shared__ float bins[RANGE];
    const int r = blockIdx.x & (NRANGE - 1);
    const int b = blockIdx.x >> 2;
    const int base = r * RANGE;

    for (int i = threadIdx.x; i < RANGE / 4; i += 256)
        ((float4*)bins)[i] = make_float4(0.f, 0.f, 0.f, 0.f);
    __syncthreads();

    const int chunk = (n_edges + NPART - 1) / NPART;
    const int cbeg = b * chunk;
    const int cend = min(cbeg + chunk, n_edges);

    for (int i = cbeg + threadIdx.x * 4; i < cend; i += 256 * 4) {
        if (i + 4 <= cend) {
            int4   rr = *(const int4*)(rows + i);
            float4 dd = *(const float4*)(dist + i);
            if ((unsigned)(rr.x - base) < RANGE) atomicAdd(&bins[rr.x - base], dd.x);
            if ((unsigned)(rr.y - base) < RANGE) atomicAdd(&bins[rr.y - base], dd.y);
            if ((unsigned)(rr.z - base) < RANGE) atomicAdd(&bins[rr.z - base], dd.z);
            if ((unsigned)(rr.w - base) < RANGE) atomicAdd(&bins[rr.w - base], dd.w);
        } else {
            for (int j = i; j < cend; ++j) {
                int rw = rows[j];
                if ((unsigned)(rw - base) < RANGE) atomicAdd(&bins[rw - base], dist[j]);
            }
        }
    }
    __syncthreads();

    float4* dst = (float4*)(part + (size_t)b * NODE_PAD + base);
    for (int i = threadIdx.x; i < RANGE / 4; i += 256)
        dst[i] = ((const float4*)bins)[i];
}

// ---------------------------------------------------------------------------
// Kernel 2: reduce the 64 scatter partials down to NGRP=4 groups (16 each).
// Fully coalesced column sweep, 196 blocks (round-4 lesson: never fuse a
// deep strided reduction into a latency-bound kernel).
// ---------------------------------------------------------------------------
__global__ __launch_bounds__(256) void reduce_partials(const float* __restrict__ part,
                                                       float* __restrict__ agg4) {
    const int g   = blockIdx.x & (NGRP - 1);
    const int blk = blockIdx.x >> 2;
    const int i   = blk * 256 + threadIdx.x;          // float4 column index
    const int nc4 = NODE_PAD / 4;
    if (i < nc4) {
        const float4* p = (const float4*)part + (size_t)g * (NPART / NGRP) * nc4 + i;
        float4 s = make_float4(0.f, 0.f, 0.f, 0.f);
#pragma unroll
        for (int c = 0; c < NPART / NGRP; ++c) {
            float4 v = p[(size_t)c * nc4];
            s.x += v.x; s.y += v.y; s.z += v.z; s.w += v.w;
        }
        ((float4*)agg4)[(size_t)g * nc4 + i] = s;
    }
}

// ---------------------------------------------------------------------------
// Kernel 3: persistent node-MLP via bf16 MFMA. 256 blocks x 512 threads
// (8 waves), each wave loops over 16-node tiles with stride 2048.
// BOTH weight layers stay resident in LDS (WL1+WL2+8 t-slices = 104.4 KB,
// 1 block/CU): staged ONCE (fp32 read, transpose+bf16-convert in regs,
// short8 stores), then ONE barrier — after that waves are fully independent
// (t round-trip is wave-private; lgkmcnt ordering suffices, no barrier).
// Next tile's h/agg prefetched during current tile's compute.
//   t = silu(h@W1 + agg*0.01*w_agg + b1); out = h + t@W2 + b2
// A-frag: lane holds A[m=lane&15][k=quad*8+j]; B-frag from WLx[n*136+k]
// (stride 136: 68 dwords = 4 mod 32 -> even bank spread on b128 reads);
// C/D: col=lane&15, row=quad*4+reg.
// ---------------------------------------------------------------------------
__global__ __launch_bounds__(512, 2) void node_mlp_mfma(
    const float* __restrict__ h,
    const float* __restrict__ agg4,  // [NGRP][NODE_PAD]
    const float* __restrict__ W1,    // [129][128] fp32 row-major
    const float* __restrict__ b1,
    const float* __restrict__ W2,    // [128][128] fp32 row-major
    const float* __restrict__ b2,
    float* __restrict__ out,
    int n_nodes, int n_tiles)
{
    __shared__ short WL1[128 * 136];       // 34816 B
    __shared__ short WL2[128 * 136];       // 34816 B
    __shared__ short t_lds[8][16 * 136];   // 34816 B   -> 104448 B total

    const int tid  = threadIdx.x;
    const int wv   = tid >> 6;
    const int lane = tid & 63;
    const int m16  = lane & 15;
    const int quad = lane >> 4;

    // ---- stage W1+W2 -> LDS (transpose + bf16 in registers, b128 stores)
    {
        const int kg = tid >> 5;     // 0..15 : k-block of 8 rows
        const int c  = tid & 31;     // 0..31 : n-block of 4 cols
        const float* s1 = W1 + (size_t)(kg * 8) * HID + c * 4;
        const float* s2 = W2 + (size_t)(kg * 8) * HID + c * 4;
        float r1[8][4], r2[8][4];
#pragma unroll
        for (int j = 0; j < 8; ++j) {
            *(float4*)r1[j] = *(const float4*)(s1 + j * HID);
            *(float4*)r2[j] = *(const float4*)(s2 + j * HID);
        }
#pragma unroll
        for (int jj = 0; jj < 4; ++jj) {
            short8 v1, v2;
#pragma unroll
            for (int j = 0; j < 8; ++j) {
                v1[j] = f2bf(r1[j][jj]);
                v2[j] = f2bf(r2[j][jj]);
            }
            *(short8*)(WL1 + (c * 4 + jj) * 136 + kg * 8) = v1;
            *(short8*)(WL2 + (c * 4 + jj) * 136 + kg * 8) = v2;
        }
    }

    // ---- per-lane column constants, hoisted over the tile loop
    float b1v[8], b2v[8], wgv[8];
#pragma unroll
    for (int nt = 0; nt < 8; ++nt) {
        int col = nt * 16 + m16;
        b1v[nt] = b1[col];
        b2v[nt] = b2[col];
        wgv[nt] = W1[(size_t)HID * HID + col];   // W1 row 128 (agg weight)
    }

    __syncthreads();   // the ONLY block-wide barrier

    const int tstride = gridDim.x * 8;
    int tile = blockIdx.x * 8 + wv;

    float4 hb[8];
    float4 ab[NGRP];
    if (tile < n_tiles) {
        int row = tile * 16 + m16;
        if (row >= n_nodes) row = n_nodes - 1;
        const float* hr = h + (size_t)row * HID + quad * 8;
#pragma unroll
        for (int kc = 0; kc < 4; ++kc) {
            hb[2 * kc]     = *(const float4*)(hr + kc * 32);
            hb[2 * kc + 1] = *(const float4*)(hr + kc * 32 + 4);
        }
#pragma unroll
        for (int g = 0; g < NGRP; ++g)
            ab[g] = *(const float4*)(agg4 + (size_t)g * NODE_PAD + tile * 16 + quad * 4);
    }

    while (tile < n_tiles) {
        const int node0 = tile * 16;

        // convert prefetched h -> bf16 A-frags
        short8 a1[4];
#pragma unroll
        for (int kc = 0; kc < 4; ++kc) {
            short8 v;
            v[0] = f2bf(hb[2 * kc].x);     v[1] = f2bf(hb[2 * kc].y);
            v[2] = f2bf(hb[2 * kc].z);     v[3] = f2bf(hb[2 * kc].w);
            v[4] = f2bf(hb[2 * kc + 1].x); v[5] = f2bf(hb[2 * kc + 1].y);
            v[6] = f2bf(hb[2 * kc + 1].z); v[7] = f2bf(hb[2 * kc + 1].w);
            a1[kc] = v;
        }
        float4 a4;
        a4.x = (ab[0].x + ab[1].x + ab[2].x + ab[3].x) * 0.01f;
        a4.y = (ab[0].y + ab[1].y + ab[2].y + ab[3].y) * 0.01f;
        a4.z = (ab[0].z + ab[1].z + ab[2].z + ab[3].z) * 0.01f;
        a4.w = (ab[0].w + ab[1].w + ab[2].w + ab[3].w) * 0.01f;

        // prefetch next tile while this one computes
        const int ntile = tile + tstride;
        if (ntile < n_tiles) {
            int row = ntile * 16 + m16;
            if (row >= n_nodes) row = n_nodes - 1;
            const float* hr = h + (size_t)row * HID + quad * 8;
#pragma unroll
            for (int kc = 0; kc < 4; ++kc) {
                hb[2 * kc]     = *(const float4*)(hr + kc * 32);
                hb[2 * kc + 1] = *(const float4*)(hr + kc * 32 + 4);
            }
#pragma unroll
            for (int g = 0; g < NGRP; ++g)
                ab[g] = *(const float4*)(agg4 + (size_t)g * NODE_PAD + ntile * 16 + quad * 4);
        }

        // ---- layer 1
#pragma unroll
        for (int nt = 0; nt < 8; ++nt) {
            floatx4 acc = {0.f, 0.f, 0.f, 0.f};
            const short* wb = WL1 + (nt * 16 + m16) * 136 + quad * 8;
#pragma unroll
            for (int kc = 0; kc < 4; ++kc) {
                short8 bfr = *(const short8*)(wb + kc * 32);
                acc = __builtin_amdgcn_mfma_f32_16x16x32_bf16(a1[kc], bfr, acc, 0, 0, 0);
            }
            int col = nt * 16 + m16;
            float av[4] = {a4.x, a4.y, a4.z, a4.w};
#pragma unroll
            for (int r = 0; r < 4; ++r) {
                float v = acc[r] + b1v[nt] + av[r] * wgv[nt];
                float sg = __builtin_amdgcn_rcpf(1.0f + __expf(-v));
                v *= sg;                       // silu
                t_lds[wv][(quad * 4 + r) * 136 + col] = f2bf(v);
            }
        }

        // wave-private C->A transform through own LDS slice (no barrier)
        short8 a2[4];
#pragma unroll
        for (int kc = 0; kc < 4; ++kc)
            a2[kc] = *(const short8*)(&t_lds[wv][m16 * 136 + kc * 32 + quad * 8]);

        // ---- layer 2 + residual epilogue
#pragma unroll
        for (int nt = 0; nt < 8; ++nt) {
            floatx4 acc = {0.f, 0.f, 0.f, 0.f};
            const short* wb = WL2 + (nt * 16 + m16) * 136 + quad * 8;
#pragma unroll
            for (int kc = 0; kc < 4; ++kc) {
                short8 bfr = *(const short8*)(wb + kc * 32);
                acc = __builtin_amdgcn_mfma_f32_16x16x32_bf16(a2[kc], bfr, acc, 0, 0, 0);
            }
            int col = nt * 16 + m16;
#pragma unroll
            for (int r = 0; r < 4; ++r) {
                int row = node0 + quad * 4 + r;
                if (row < n_nodes) {
                    size_t off = (size_t)row * HID + col;
                    out[off] = h[off] + acc[r] + b2v[nt];
                }
            }
        }

        tile = ntile;
    }
}

// ---------------------------------------------------------------------------
// Launch.  Inputs (setup_inputs order):
//  0 h[50000*128] f32 | 1 edges[2*800000] i32 | 2 distances[800000] f32
//  3..8 edge-MLP weights (DEAD CODE, unused)
//  9 W_n1[129*128] | 10 b_n1[128] | 11 W_n2[128*128] | 12 b_n2[128]
// d_ws: part f32[NPART][NODE_PAD] (12.8 MB) | agg4 f32[NGRP][NODE_PAD]
//       (0.8 MB).  No zeroing needed: every element is overwritten.
// ---------------------------------------------------------------------------
extern "C" void kernel_launch(void* const* d_in, const int* in_sizes, int n_in,
                              void* d_out, int out_size, void* d_ws, size_t ws_size,
                              hipStream_t stream) {
    const float* h     = (const float*)d_in[0];
    const int*   edges = (const int*)d_in[1];
    const float* dist  = (const float*)d_in[2];
    const float* W1    = (const float*)d_in[9];
    const float* b1    = (const float*)d_in[10];
    const float* W2    = (const float*)d_in[11];
    const float* b2    = (const float*)d_in[12];
    float* out = (float*)d_out;

    const int n_nodes = in_sizes[0] / HID;
    const int n_edges = in_sizes[2];
    const int* rows = edges;   // edges[0, :]

    float* part = (float*)d_ws;
    float* agg4 = part + (size_t)NPART * NODE_PAD;

    scatter_lds<<<NRANGE * NPART, 256, 0, stream>>>(rows, dist, part, n_edges);

    reduce_partials<<<NGRP * ((NODE_PAD / 4 + 255) / 256), 256, 0, stream>>>(part, agg4);

    const int n_tiles = (n_nodes + 15) / 16;
    node_mlp_mfma<<<256, 512, 0, stream>>>(h, agg4, W1, b1, W2, b2, out,
                                           n_nodes, n_tiles);
}

// Round 8
// 129.931 us; speedup vs baseline: 1.0749x; 1.0749x over previous
//
#include <hip/hip_runtime.h>

#define HID 128
#define NODE_PAD 50048   // padded node count (multiple of 16; covers 50000)
#define NRANGE 4         // node ranges (LDS histogram per range)
#define RANGE 12512      // NODE_PAD / NRANGE  (48.9 KB of LDS bins)
#define NPART 64         // edge chunks = partial aggregate buffers
#define NGRP 4           // reduced partial groups read by the MLP

typedef __attribute__((ext_vector_type(8))) short short8;   // bf16x8 A/B frag (4 VGPRs)
typedef __attribute__((ext_vector_type(4))) float floatx4;  // C/D frag

// fp32 -> bf16 (RNE) as raw short
__device__ __forceinline__ short f2bf(float f) {
    unsigned u = __builtin_bit_cast(unsigned, f);
    unsigned r = (u + 0x7FFFu + ((u >> 16) & 1u)) >> 16;
    return (short)r;
}

// ---------------------------------------------------------------------------
// Kernel 1: scatter-add with ZERO global atomics (round-3 lesson: device
// fp32 atomics bottleneck at ~19 G/s with 32 B write-through each).
// Block (r,b) bins node range r of edge chunk b into LDS, then streams the
// bins to part[b] with plain coalesced stores.
// ---------------------------------------------------------------------------
__global__ __launch_bounds__(256) void scatter_lds(const int* __restrict__ rows,
                                                   const float* __restrict__ dist,
                                                   float* __restrict__ part,
                                                   int n_edges) {
    __shared__ float bins[RANGE];
    const int r = blockIdx.x & (NRANGE - 1);
    const int b = blockIdx.x >> 2;
    const int base = r * RANGE;

    for (int i = threadIdx.x; i < RANGE / 4; i += 256)
        ((float4*)bins)[i] = make_float4(0.f, 0.f, 0.f, 0.f);
    __syncthreads();

    const int chunk = (n_edges + NPART - 1) / NPART;
    const int cbeg = b * chunk;
    const int cend = min(cbeg + chunk, n_edges);

    for (int i = cbeg + threadIdx.x * 4; i < cend; i += 256 * 4) {
        if (i + 4 <= cend) {
            int4   rr = *(const int4*)(rows + i);
            float4 dd = *(const float4*)(dist + i);
            if ((unsigned)(rr.x - base) < RANGE) atomicAdd(&bins[rr.x - base], dd.x);
            if ((unsigned)(rr.y - base) < RANGE) atomicAdd(&bins[rr.y - base], dd.y);
            if ((unsigned)(rr.z - base) < RANGE) atomicAdd(&bins[rr.z - base], dd.z);
            if ((unsigned)(rr.w - base) < RANGE) atomicAdd(&bins[rr.w - base], dd.w);
        } else {
            for (int j = i; j < cend; ++j) {
                int rw = rows[j];
                if ((unsigned)(rw - base) < RANGE) atomicAdd(&bins[rw - base], dist[j]);
            }
        }
    }
    __syncthreads();

    float4* dst = (float4*)(part + (size_t)b * NODE_PAD + base);
    for (int i = threadIdx.x; i < RANGE / 4; i += 256)
        dst[i] = ((const float4*)bins)[i];
}

// ---------------------------------------------------------------------------
// Kernel 2: reduce the 64 scatter partials down to NGRP=4 groups (16 each).
// Fully coalesced column sweep, 196 blocks (round-4 lesson: never fuse a
// deep strided reduction into a latency-bound kernel).
// ---------------------------------------------------------------------------
__global__ __launch_bounds__(256) void reduce_partials(const float* __restrict__ part,
                                                       float* __restrict__ agg4) {
    const int g   = blockIdx.x & (NGRP - 1);
    const int blk = blockIdx.x >> 2;
    const int i   = blk * 256 + threadIdx.x;          // float4 column index
    const int nc4 = NODE_PAD / 4;
    if (i < nc4) {
        const float4* p = (const float4*)part + (size_t)g * (NPART / NGRP) * nc4 + i;
        float4 s = make_float4(0.f, 0.f, 0.f, 0.f);
#pragma unroll
        for (int c = 0; c < NPART / NGRP; ++c) {
            float4 v = p[(size_t)c * nc4];
            s.x += v.x; s.y += v.y; s.z += v.z; s.w += v.w;
        }
        ((float4*)agg4)[(size_t)g * nc4 + i] = s;
    }
}

// ---------------------------------------------------------------------------
// Kernel 3: node MLP via bf16 MFMA — round-6 structure (the best measured:
// 512-thread blocks = 8 one-tile waves, weights staged one layer at a time
// into a reused 34.8 KB LDS buffer, 69.6 KB total -> 2 blocks/CU = 16
// waves/CU). Round-7 lesson: persistent grid at 1 block/CU regressed
// (1.5 tiles/wave amortized nothing, occupancy halved) — reverted.
// New vs round 6: fp32 weights are transposed + bf16-converted IN REGISTERS
// during staging (separate convert_weights launch eliminated), and agg is
// read as NGRP=4 groups instead of 8.
//   t = silu(h@W1 + agg*0.01*w_agg + b1); out = h + t@W2 + b2
// A-frag: lane holds A[m=lane&15][k=quad*8+j]; B-frag from WL[n*136+k]
// (stride 136 shorts -> uniform 8 dword-accesses/bank on b128 reads);
// C/D: col=lane&15, row=quad*4+reg; t round-trips wave-private LDS
// (C-layout -> A-layout, lgkmcnt ordering, no extra barrier).
// ---------------------------------------------------------------------------
__global__ __launch_bounds__(512) void node_mlp_mfma(
    const float* __restrict__ h,
    const float* __restrict__ agg4,  // [NGRP][NODE_PAD]
    const float* __restrict__ W1,    // [129][128] fp32 row-major
    const float* __restrict__ b1,
    const float* __restrict__ W2,    // [128][128] fp32 row-major
    const float* __restrict__ b2,
    float* __restrict__ out,
    int n_nodes)
{
    __shared__ short WL[128 * 136];        // 34816 B, one layer at a time
    __shared__ short t_lds[8][16 * 136];   // 34816 B, per-wave t slices

    const int tid  = threadIdx.x;
    const int wv   = tid >> 6;
    const int lane = tid & 63;
    const int m16  = lane & 15;
    const int quad = lane >> 4;
    const int node0 = blockIdx.x * 128 + wv * 16;

    // ---- A fragments for layer 1 (h rows, fp32 -> bf16 in regs); issue early
    short8 a1[4];
    {
        int row = node0 + m16;
        if (row >= n_nodes) row = n_nodes - 1;
        const float* hr = h + (size_t)row * HID + quad * 8;
#pragma unroll
        for (int kc = 0; kc < 4; ++kc) {
            float4 x0 = *(const float4*)(hr + kc * 32);
            float4 x1 = *(const float4*)(hr + kc * 32 + 4);
            short8 v;
            v[0] = f2bf(x0.x); v[1] = f2bf(x0.y); v[2] = f2bf(x0.z); v[3] = f2bf(x0.w);
            v[4] = f2bf(x1.x); v[5] = f2bf(x1.y); v[6] = f2bf(x1.z); v[7] = f2bf(x1.w);
            a1[kc] = v;
        }
    }

    // agg for this lane's 4 C-rows: sum the 4 reduced groups, scale by 1/100
    float4 a4;
    {
        float4 s = make_float4(0.f, 0.f, 0.f, 0.f);
#pragma unroll
        for (int g = 0; g < NGRP; ++g) {
            float4 p = *(const float4*)(agg4 + (size_t)g * NODE_PAD + node0 + quad * 4);
            s.x += p.x; s.y += p.y; s.z += p.z; s.w += p.w;
        }
        a4.x = s.x * 0.01f; a4.y = s.y * 0.01f; a4.z = s.z * 0.01f; a4.w = s.w * 0.01f;
    }

    // ---- staging thread mapping: kg = k-block of 8 rows, c = n-block of 4
    const int kg = tid >> 5;     // 0..15
    const int cc = tid & 31;     // 0..31

    // ---- stage W1 -> LDS (fp32 read, transpose + bf16 convert in regs)
    {
        const float* src = W1 + (size_t)(kg * 8) * HID + cc * 4;
        float r[8][4];
#pragma unroll
        for (int j = 0; j < 8; ++j)
            *(float4*)r[j] = *(const float4*)(src + j * HID);
#pragma unroll
        for (int jj = 0; jj < 4; ++jj) {
            short8 v;
#pragma unroll
            for (int j = 0; j < 8; ++j) v[j] = f2bf(r[j][jj]);
            *(short8*)(WL + (cc * 4 + jj) * 136 + kg * 8) = v;
        }
    }
    __syncthreads();

    // ---- layer 1: 8 col-tiles of 16, K=128 in 4 MFMA steps each
#pragma unroll
    for (int nt = 0; nt < 8; ++nt) {
        floatx4 acc = {0.f, 0.f, 0.f, 0.f};
        const short* wb = WL + (nt * 16 + m16) * 136 + quad * 8;
#pragma unroll
        for (int kc = 0; kc < 4; ++kc) {
            short8 bfr = *(const short8*)(wb + kc * 32);
            acc = __builtin_amdgcn_mfma_f32_16x16x32_bf16(a1[kc], bfr, acc, 0, 0, 0);
        }
        int col = nt * 16 + m16;
        float bias = b1[col];
        float wagg = W1[(size_t)HID * HID + col];   // W1 row 128 (agg weight)
        float av[4] = {a4.x, a4.y, a4.z, a4.w};
#pragma unroll
        for (int r = 0; r < 4; ++r) {
            float v = acc[r] + bias + av[r] * wagg;
            float sg = __builtin_amdgcn_rcpf(1.0f + __expf(-v));
            v *= sg;                       // silu
            t_lds[wv][(quad * 4 + r) * 136 + col] = f2bf(v);
        }
    }

    __syncthreads();   // all waves done reading W1 before overwrite

    // ---- stage W2 into the SAME LDS buffer (fp32, transpose+convert)
    {
        const float* src = W2 + (size_t)(kg * 8) * HID + cc * 4;
        float r[8][4];
#pragma unroll
        for (int j = 0; j < 8; ++j)
            *(float4*)r[j] = *(const float4*)(src + j * HID);
#pragma unroll
        for (int jj = 0; jj < 4; ++jj) {
            short8 v;
#pragma unroll
            for (int j = 0; j < 8; ++j) v[j] = f2bf(r[j][jj]);
            *(short8*)(WL + (cc * 4 + jj) * 136 + kg * 8) = v;
        }
    }
    __syncthreads();

    // ---- A fragments for layer 2 from own LDS slice (A-layout, 16B aligned)
    short8 a2[4];
#pragma unroll
    for (int kc = 0; kc < 4; ++kc)
        a2[kc] = *(const short8*)(&t_lds[wv][m16 * 136 + kc * 32 + quad * 8]);

    // ---- layer 2 + residual epilogue
#pragma unroll
    for (int nt = 0; nt < 8; ++nt) {
        floatx4 acc = {0.f, 0.f, 0.f, 0.f};
        const short* wb = WL + (nt * 16 + m16) * 136 + quad * 8;
#pragma unroll
        for (int kc = 0; kc < 4; ++kc) {
            short8 bfr = *(const short8*)(wb + kc * 32);
            acc = __builtin_amdgcn_mfma_f32_16x16x32_bf16(a2[kc], bfr, acc, 0, 0, 0);
        }
        int col = nt * 16 + m16;
        float bias = b2[col];
#pragma unroll
        for (int r = 0; r < 4; ++r) {
            int row = node0 + quad * 4 + r;
            if (row < n_nodes) {
                size_t off = (size_t)row * HID + col;
                out[off] = h[off] + acc[r] + bias;
            }
        }
    }
}

// ---------------------------------------------------------------------------
// Launch.  Inputs (setup_inputs order):
//  0 h[50000*128] f32 | 1 edges[2*800000] i32 | 2 distances[800000] f32
//  3..8 edge-MLP weights (DEAD CODE, unused)
//  9 W_n1[129*128] | 10 b_n1[128] | 11 W_n2[128*128] | 12 b_n2[128]
// d_ws: part f32[NPART][NODE_PAD] (12.8 MB) | agg4 f32[NGRP][NODE_PAD]
//       (0.8 MB).  No zeroing needed: every element is overwritten.
// ---------------------------------------------------------------------------
extern "C" void kernel_launch(void* const* d_in, const int* in_sizes, int n_in,
                              void* d_out, int out_size, void* d_ws, size_t ws_size,
                              hipStream_t stream) {
    const float* h     = (const float*)d_in[0];
    const int*   edges = (const int*)d_in[1];
    const float* dist  = (const float*)d_in[2];
    const float* W1    = (const float*)d_in[9];
    const float* b1    = (const float*)d_in[10];
    const float* W2    = (const float*)d_in[11];
    const float* b2    = (const float*)d_in[12];
    float* out = (float*)d_out;

    const int n_nodes = in_sizes[0] / HID;
    const int n_edges = in_sizes[2];
    const int* rows = edges;   // edges[0, :]

    float* part = (float*)d_ws;
    float* agg4 = part + (size_t)NPART * NODE_PAD;

    scatter_lds<<<NRANGE * NPART, 256, 0, stream>>>(rows, dist, part, n_edges);

    reduce_partials<<<NGRP * ((NODE_PAD / 4 + 255) / 256), 256, 0, stream>>>(part, agg4);

    const int blocks = (n_nodes + 127) / 128;
    node_mlp_mfma<<<blocks, 512, 0, stream>>>(h, agg4, W1, b1, W2, b2, out, n_nodes);
}

// Round 9
// 125.011 us; speedup vs baseline: 1.1172x; 1.0394x over previous
//
#include <hip/hip_runtime.h>

#define HID 128
#define NODE_PAD 50048   // padded node count (multiple of 16; covers 50000)
#define NRANGE 4         // node ranges (LDS histogram per range)
#define RANGE 12512      // NODE_PAD / NRANGE  (48.9 KB of LDS bins)
#define NPART 64         // edge chunks = partial aggregate buffers
#define NGRP 4           // reduced partial groups read by the MLP

typedef __attribute__((ext_vector_type(8))) short short8;   // bf16x8 (4 VGPRs)
typedef __attribute__((ext_vector_type(4))) float floatx4;  // C/D frag

// fp32 -> bf16 (RNE) as raw short
__device__ __forceinline__ short f2bf(float f) {
    unsigned u = __builtin_bit_cast(unsigned, f);
    unsigned r = (u + 0x7FFFu + ((u >> 16) & 1u)) >> 16;
    return (short)r;
}
// bf16 (raw short) -> fp32
__device__ __forceinline__ float bf2f(short s) {
    unsigned u = ((unsigned)(unsigned short)s) << 16;
    return __builtin_bit_cast(float, u);
}

// ---------------------------------------------------------------------------
// Kernel 1: scatter-add with ZERO global atomics (round-3 lesson: device
// fp32 atomics bottleneck at ~19 G/s with 32 B write-through each).
// Block (r,b) bins node range r of edge chunk b into fp32 LDS, then streams
// the bins to part[b] as BF16 (halves part traffic; error ~2e-5 downstream).
// ---------------------------------------------------------------------------
__global__ __launch_bounds__(256) void scatter_lds(const int* __restrict__ rows,
                                                   const float* __restrict__ dist,
                                                   unsigned short* __restrict__ part,
                                                   int n_edges) {
    __shared__ float bins[RANGE];
    const int r = blockIdx.x & (NRANGE - 1);
    const int b = blockIdx.x >> 2;
    const int base = r * RANGE;

    for (int i = threadIdx.x; i < RANGE / 4; i += 256)
        ((float4*)bins)[i] = make_float4(0.f, 0.f, 0.f, 0.f);
    __syncthreads();

    const int chunk = (n_edges + NPART - 1) / NPART;
    const int cbeg = b * chunk;
    const int cend = min(cbeg + chunk, n_edges);

    for (int i = cbeg + threadIdx.x * 4; i < cend; i += 256 * 4) {
        if (i + 4 <= cend) {
            int4   rr = *(const int4*)(rows + i);
            float4 dd = *(const float4*)(dist + i);
            if ((unsigned)(rr.x - base) < RANGE) atomicAdd(&bins[rr.x - base], dd.x);
            if ((unsigned)(rr.y - base) < RANGE) atomicAdd(&bins[rr.y - base], dd.y);
            if ((unsigned)(rr.z - base) < RANGE) atomicAdd(&bins[rr.z - base], dd.z);
            if ((unsigned)(rr.w - base) < RANGE) atomicAdd(&bins[rr.w - base], dd.w);
        } else {
            for (int j = i; j < cend; ++j) {
                int rw = rows[j];
                if ((unsigned)(rw - base) < RANGE) atomicAdd(&bins[rw - base], dist[j]);
            }
        }
    }
    __syncthreads();

    unsigned short* dst = part + (size_t)b * NODE_PAD + base;
    for (int i = threadIdx.x; i < RANGE / 8; i += 256) {
        float4 lo = ((const float4*)bins)[i * 2];
        float4 hi = ((const float4*)bins)[i * 2 + 1];
        short8 v;
        v[0] = f2bf(lo.x); v[1] = f2bf(lo.y); v[2] = f2bf(lo.z); v[3] = f2bf(lo.w);
        v[4] = f2bf(hi.x); v[5] = f2bf(hi.y); v[6] = f2bf(hi.z); v[7] = f2bf(hi.w);
        *(short8*)(dst + i * 8) = v;
    }
}

// ---------------------------------------------------------------------------
// Kernel 2: reduce the 64 bf16 partials down to NGRP=4 fp32 groups (16 each).
// short8 loads (16 B/lane), fp32 accumulate, float4 stores. 100 blocks,
// ~7 MB traffic (round-4 lesson: never fuse this into the MLP).
// ---------------------------------------------------------------------------
__global__ __launch_bounds__(256) void reduce_partials(
    const unsigned short* __restrict__ part,
    float* __restrict__ agg4) {
    const int g   = blockIdx.x & (NGRP - 1);
    const int idx = (blockIdx.x >> 2) * 256 + threadIdx.x;   // 8-node group
    const int n8  = NODE_PAD / 8;
    if (idx < n8) {
        float s[8] = {0.f, 0.f, 0.f, 0.f, 0.f, 0.f, 0.f, 0.f};
#pragma unroll
        for (int c = 0; c < NPART / NGRP; ++c) {
            const unsigned short* p =
                part + (size_t)(g * (NPART / NGRP) + c) * NODE_PAD + idx * 8;
            short8 v = *(const short8*)p;
#pragma unroll
            for (int j = 0; j < 8; ++j) s[j] += bf2f(v[j]);
        }
        float* o = agg4 + (size_t)g * NODE_PAD + idx * 8;
        *(float4*)o       = make_float4(s[0], s[1], s[2], s[3]);
        *(float4*)(o + 4) = make_float4(s[4], s[5], s[6], s[7]);
    }
}

// ---------------------------------------------------------------------------
// Kernel 3: node MLP via bf16 MFMA — round-6/8 structure (best measured):
// 512-thread blocks = 8 one-tile waves, fp32 weights transposed+converted in
// registers into a reused 34.8 KB LDS buffer one layer at a time (69.6 KB
// total -> 2 blocks/CU = 16 waves/CU; round-7 lesson: persistent 1-block/CU
// grid regresses).
// NEW: epilogue routes layer-2 acc through a wave-private 16x17 fp32 LDS
// scratch (reuses the consumed t slice; per-wave DS ops are in-order -> no
// barrier; stride 17 keeps banks <=2-way) so h re-read + store become
// float4 (global instrs 64 -> 16 per lane in the latency tail).
//   t = silu(h@W1 + agg*0.01*w_agg + b1); out = h + t@W2 + b2
// ---------------------------------------------------------------------------
__global__ __launch_bounds__(512) void node_mlp_mfma(
    const float* __restrict__ h,
    const float* __restrict__ agg4,  // [NGRP][NODE_PAD]
    const float* __restrict__ W1,    // [129][128] fp32 row-major
    const float* __restrict__ b1,
    const float* __restrict__ W2,    // [128][128] fp32 row-major
    const float* __restrict__ b2,
    float* __restrict__ out,
    int n_nodes)
{
    __shared__ short WL[128 * 136];        // 34816 B, one layer at a time
    __shared__ short t_lds[8][16 * 136];   // 34816 B, per-wave t / scratch

    const int tid  = threadIdx.x;
    const int wv   = tid >> 6;
    const int lane = tid & 63;
    const int m16  = lane & 15;
    const int quad = lane >> 4;
    const int node0 = blockIdx.x * 128 + wv * 16;

    // ---- A fragments for layer 1 (h rows, fp32 -> bf16 in regs); issue early
    short8 a1[4];
    {
        int row = node0 + m16;
        if (row >= n_nodes) row = n_nodes - 1;
        const float* hr = h + (size_t)row * HID + quad * 8;
#pragma unroll
        for (int kc = 0; kc < 4; ++kc) {
            float4 x0 = *(const float4*)(hr + kc * 32);
            float4 x1 = *(const float4*)(hr + kc * 32 + 4);
            short8 v;
            v[0] = f2bf(x0.x); v[1] = f2bf(x0.y); v[2] = f2bf(x0.z); v[3] = f2bf(x0.w);
            v[4] = f2bf(x1.x); v[5] = f2bf(x1.y); v[6] = f2bf(x1.z); v[7] = f2bf(x1.w);
            a1[kc] = v;
        }
    }

    // agg for this lane's 4 C-rows: sum the 4 reduced groups, scale by 1/100
    float4 a4;
    {
        float4 s = make_float4(0.f, 0.f, 0.f, 0.f);
#pragma unroll
        for (int g = 0; g < NGRP; ++g) {
            float4 p = *(const float4*)(agg4 + (size_t)g * NODE_PAD + node0 + quad * 4);
            s.x += p.x; s.y += p.y; s.z += p.z; s.w += p.w;
        }
        a4.x = s.x * 0.01f; a4.y = s.y * 0.01f; a4.z = s.z * 0.01f; a4.w = s.w * 0.01f;
    }

    // ---- staging thread mapping: kg = k-block of 8 rows, cc = n-block of 4
    const int kg = tid >> 5;     // 0..15
    const int cc = tid & 31;     // 0..31

    // ---- stage W1 -> LDS (fp32 read, transpose + bf16 convert in regs)
    {
        const float* src = W1 + (size_t)(kg * 8) * HID + cc * 4;
        float r[8][4];
#pragma unroll
        for (int j = 0; j < 8; ++j)
            *(float4*)r[j] = *(const float4*)(src + j * HID);
#pragma unroll
        for (int jj = 0; jj < 4; ++jj) {
            short8 v;
#pragma unroll
            for (int j = 0; j < 8; ++j) v[j] = f2bf(r[j][jj]);
            *(short8*)(WL + (cc * 4 + jj) * 136 + kg * 8) = v;
        }
    }
    __syncthreads();

    // ---- layer 1: 8 col-tiles of 16, K=128 in 4 MFMA steps each
#pragma unroll
    for (int nt = 0; nt < 8; ++nt) {
        floatx4 acc = {0.f, 0.f, 0.f, 0.f};
        const short* wb = WL + (nt * 16 + m16) * 136 + quad * 8;
#pragma unroll
        for (int kc = 0; kc < 4; ++kc) {
            short8 bfr = *(const short8*)(wb + kc * 32);
            acc = __builtin_amdgcn_mfma_f32_16x16x32_bf16(a1[kc], bfr, acc, 0, 0, 0);
        }
        int col = nt * 16 + m16;
        float bias = b1[col];
        float wagg = W1[(size_t)HID * HID + col];   // W1 row 128 (agg weight)
        float av[4] = {a4.x, a4.y, a4.z, a4.w};
#pragma unroll
        for (int r = 0; r < 4; ++r) {
            float v = acc[r] + bias + av[r] * wagg;
            float sg = __builtin_amdgcn_rcpf(1.0f + __expf(-v));
            v *= sg;                       // silu
            t_lds[wv][(quad * 4 + r) * 136 + col] = f2bf(v);
        }
    }

    __syncthreads();   // all waves done reading W1 before overwrite

    // ---- stage W2 into the SAME LDS buffer (fp32, transpose+convert)
    {
        const float* src = W2 + (size_t)(kg * 8) * HID + cc * 4;
        float r[8][4];
#pragma unroll
        for (int j = 0; j < 8; ++j)
            *(float4*)r[j] = *(const float4*)(src + j * HID);
#pragma unroll
        for (int jj = 0; jj < 4; ++jj) {
            short8 v;
#pragma unroll
            for (int j = 0; j < 8; ++j) v[j] = f2bf(r[j][jj]);
            *(short8*)(WL + (cc * 4 + jj) * 136 + kg * 8) = v;
        }
    }
    __syncthreads();

    // ---- A fragments for layer 2 from own LDS slice (A-layout, 16B aligned)
    short8 a2[4];
#pragma unroll
    for (int kc = 0; kc < 4; ++kc)
        a2[kc] = *(const short8*)(&t_lds[wv][m16 * 136 + kc * 32 + quad * 8]);

    // per-lane b2 in C-layout columns (write side of the scratch transpose)
    float b2v[8];
#pragma unroll
    for (int nt = 0; nt < 8; ++nt) b2v[nt] = b2[nt * 16 + m16];

    // ---- layer 2 + residual epilogue via wave-private LDS transpose.
    // t slice is consumed (a2 read above); per-wave DS ops execute in order,
    // so no barrier is needed between t reads / scratch writes / reads.
    float* scratch = (float*)&t_lds[wv][0];   // 16 rows x 17 fp32 (1088 B)
    const int erow = lane & 15;               // row handled on the read side
    const int ecg  = lane >> 4;               // 4-col group on the read side
#pragma unroll
    for (int nt = 0; nt < 8; ++nt) {
        floatx4 acc = {0.f, 0.f, 0.f, 0.f};
        const short* wb = WL + (nt * 16 + m16) * 136 + quad * 8;
#pragma unroll
        for (int kc = 0; kc < 4; ++kc) {
            short8 bfr = *(const short8*)(wb + kc * 32);
            acc = __builtin_amdgcn_mfma_f32_16x16x32_bf16(a2[kc], bfr, acc, 0, 0, 0);
        }
        // C-layout (col=m16, row=quad*4+r) -> scratch, bias fused
#pragma unroll
        for (int r = 0; r < 4; ++r)
            scratch[(quad * 4 + r) * 17 + m16] = acc[r] + b2v[nt];
        // transposed read + residual + coalesced float4 store
        float4 sv = *(const float4*)(scratch + erow * 17 + ecg * 4);
        int row = node0 + erow;
        if (row < n_nodes) {
            size_t off = (size_t)row * HID + nt * 16 + ecg * 4;
            float4 hv = *(const float4*)(h + off);
            float4 o = make_float4(hv.x + sv.x, hv.y + sv.y,
                                   hv.z + sv.z, hv.w + sv.w);
            *(float4*)(out + off) = o;
        }
    }
}

// ---------------------------------------------------------------------------
// Launch.  Inputs (setup_inputs order):
//  0 h[50000*128] f32 | 1 edges[2*800000] i32 | 2 distances[800000] f32
//  3..8 edge-MLP weights (DEAD CODE, unused)
//  9 W_n1[129*128] | 10 b_n1[128] | 11 W_n2[128*128] | 12 b_n2[128]
// d_ws: part bf16[NPART][NODE_PAD] (6.4 MB) | agg4 f32[NGRP][NODE_PAD]
//       (0.8 MB).  No zeroing needed: every element is overwritten.
// ---------------------------------------------------------------------------
extern "C" void kernel_launch(void* const* d_in, const int* in_sizes, int n_in,
                              void* d_out, int out_size, void* d_ws, size_t ws_size,
                              hipStream_t stream) {
    const float* h     = (const float*)d_in[0];
    const int*   edges = (const int*)d_in[1];
    const float* dist  = (const float*)d_in[2];
    const float* W1    = (const float*)d_in[9];
    const float* b1    = (const float*)d_in[10];
    const float* W2    = (const float*)d_in[11];
    const float* b2    = (const float*)d_in[12];
    float* out = (float*)d_out;

    const int n_nodes = in_sizes[0] / HID;
    const int n_edges = in_sizes[2];
    const int* rows = edges;   // edges[0, :]

    unsigned short* part = (unsigned short*)d_ws;
    float* agg4 = (float*)(part + (size_t)NPART * NODE_PAD);

    scatter_lds<<<NRANGE * NPART, 256, 0, stream>>>(rows, dist, part, n_edges);

    reduce_partials<<<NGRP * ((NODE_PAD / 8 + 255) / 256), 256, 0, stream>>>(part, agg4);

    const int blocks = (n_nodes + 127) / 128;
    node_mlp_mfma<<<blocks, 512, 0, stream>>>(h, agg4, W1, b1, W2, b2, out, n_nodes);
}

// Round 10
// 124.271 us; speedup vs baseline: 1.1239x; 1.0060x over previous
//
#include <hip/hip_runtime.h>

#define HID 128
#define NODE_PAD 50048   // padded node count (multiple of 16; covers 50000)
#define NRANGE 4         // node ranges (LDS histogram per range)
#define RANGE 12512      // NODE_PAD / NRANGE  (48.9 KB of LDS bins)
#define NPART 64         // edge chunks = partial aggregate buffers
#define NGRP 4           // reduced partial groups read by the MLP

typedef __attribute__((ext_vector_type(8))) short short8;   // bf16x8 (4 VGPRs)
typedef __attribute__((ext_vector_type(4))) float floatx4;  // C/D frag

// fp32 -> bf16 (RNE) as raw short
__device__ __forceinline__ short f2bf(float f) {
    unsigned u = __builtin_bit_cast(unsigned, f);
    unsigned r = (u + 0x7FFFu + ((u >> 16) & 1u)) >> 16;
    return (short)r;
}
// bf16 (raw short) -> fp32
__device__ __forceinline__ float bf2f(short s) {
    unsigned u = ((unsigned)(unsigned short)s) << 16;
    return __builtin_bit_cast(float, u);
}

// ---------------------------------------------------------------------------
// Kernel 1: scatter-add with ZERO global atomics (round-3 lesson: device
// fp32 atomics bottleneck at ~19 G/s with 32 B write-through each).
// Block (r,b) bins node range r of edge chunk b into fp32 LDS, then streams
// the bins to part[b] as BF16.
// XCD swizzle (round-10): the 4 range-blocks of a chunk get blockIdx ids
// differing by 8/16/24 so the round-robin workgroup->XCD dispatch puts them
// on the SAME XCD; 3 of the 4 chunk scans then hit that XCD's L2 instead of
// HBM (edge fetch 25.6 -> ~7 MB). Pure index remap: correctness-neutral if
// the dispatch heuristic is wrong.
// ---------------------------------------------------------------------------
__global__ __launch_bounds__(256) void scatter_lds(const int* __restrict__ rows,
                                                   const float* __restrict__ dist,
                                                   unsigned short* __restrict__ part,
                                                   int n_edges) {
    __shared__ float bins[RANGE];
    const int i = blockIdx.x;                      // 0..255
    const int b = (i & 7) * (NPART / 8) + (i >> 5);   // chunk, co-located per XCD
    const int r = (i >> 3) & (NRANGE - 1);            // node range
    const int base = r * RANGE;

    for (int t = threadIdx.x; t < RANGE / 4; t += 256)
        ((float4*)bins)[t] = make_float4(0.f, 0.f, 0.f, 0.f);
    __syncthreads();

    const int chunk = (n_edges + NPART - 1) / NPART;
    const int cbeg = b * chunk;
    const int cend = min(cbeg + chunk, n_edges);

    for (int e = cbeg + threadIdx.x * 4; e < cend; e += 256 * 4) {
        if (e + 4 <= cend) {
            int4   rr = *(const int4*)(rows + e);
            float4 dd = *(const float4*)(dist + e);
            if ((unsigned)(rr.x - base) < RANGE) atomicAdd(&bins[rr.x - base], dd.x);
            if ((unsigned)(rr.y - base) < RANGE) atomicAdd(&bins[rr.y - base], dd.y);
            if ((unsigned)(rr.z - base) < RANGE) atomicAdd(&bins[rr.z - base], dd.z);
            if ((unsigned)(rr.w - base) < RANGE) atomicAdd(&bins[rr.w - base], dd.w);
        } else {
            for (int j = e; j < cend; ++j) {
                int rw = rows[j];
                if ((unsigned)(rw - base) < RANGE) atomicAdd(&bins[rw - base], dist[j]);
            }
        }
    }
    __syncthreads();

    unsigned short* dst = part + (size_t)b * NODE_PAD + base;
    for (int t = threadIdx.x; t < RANGE / 8; t += 256) {
        float4 lo = ((const float4*)bins)[t * 2];
        float4 hi = ((const float4*)bins)[t * 2 + 1];
        short8 v;
        v[0] = f2bf(lo.x); v[1] = f2bf(lo.y); v[2] = f2bf(lo.z); v[3] = f2bf(lo.w);
        v[4] = f2bf(hi.x); v[5] = f2bf(hi.y); v[6] = f2bf(hi.z); v[7] = f2bf(hi.w);
        *(short8*)(dst + t * 8) = v;
    }
}

// ---------------------------------------------------------------------------
// Kernel 2: reduce the 64 bf16 partials down to NGRP=4 fp32 groups (16 each).
// short8 loads (16 B/lane), fp32 accumulate, float4 stores. (Round-4 lesson:
// never fuse this into the latency-bound MLP.)
// ---------------------------------------------------------------------------
__global__ __launch_bounds__(256) void reduce_partials(
    const unsigned short* __restrict__ part,
    float* __restrict__ agg4) {
    const int g   = blockIdx.x & (NGRP - 1);
    const int idx = (blockIdx.x >> 2) * 256 + threadIdx.x;   // 8-node group
    const int n8  = NODE_PAD / 8;
    if (idx < n8) {
        float s[8] = {0.f, 0.f, 0.f, 0.f, 0.f, 0.f, 0.f, 0.f};
#pragma unroll
        for (int c = 0; c < NPART / NGRP; ++c) {
            const unsigned short* p =
                part + (size_t)(g * (NPART / NGRP) + c) * NODE_PAD + idx * 8;
            short8 v = *(const short8*)p;
#pragma unroll
            for (int j = 0; j < 8; ++j) s[j] += bf2f(v[j]);
        }
        float* o = agg4 + (size_t)g * NODE_PAD + idx * 8;
        *(float4*)o       = make_float4(s[0], s[1], s[2], s[3]);
        *(float4*)(o + 4) = make_float4(s[4], s[5], s[6], s[7]);
    }
}

// ---------------------------------------------------------------------------
// Kernel 3: node MLP via bf16 MFMA — round-6/8/9 structure (best measured):
// 512-thread blocks = 8 one-tile waves, fp32 weights transposed+converted in
// registers into a reused 34.8 KB LDS buffer one layer at a time (69.6 KB
// total -> 2 blocks/CU = 16 waves/CU; round-7 lesson: persistent 1-block/CU
// grid regresses). Epilogue routes layer-2 acc through a wave-private 16x17
// fp32 LDS scratch (reuses the consumed t slice; per-wave DS ops in-order ->
// no barrier) so h re-read + store are float4-coalesced.
//   t = silu(h@W1 + agg*0.01*w_agg + b1); out = h + t@W2 + b2
// ---------------------------------------------------------------------------
__global__ __launch_bounds__(512) void node_mlp_mfma(
    const float* __restrict__ h,
    const float* __restrict__ agg4,  // [NGRP][NODE_PAD]
    const float* __restrict__ W1,    // [129][128] fp32 row-major
    const float* __restrict__ b1,
    const float* __restrict__ W2,    // [128][128] fp32 row-major
    const float* __restrict__ b2,
    float* __restrict__ out,
    int n_nodes)
{
    __shared__ short WL[128 * 136];        // 34816 B, one layer at a time
    __shared__ short t_lds[8][16 * 136];   // 34816 B, per-wave t / scratch

    const int tid  = threadIdx.x;
    const int wv   = tid >> 6;
    const int lane = tid & 63;
    const int m16  = lane & 15;
    const int quad = lane >> 4;
    const int node0 = blockIdx.x * 128 + wv * 16;

    // ---- A fragments for layer 1 (h rows, fp32 -> bf16 in regs); issue early
    short8 a1[4];
    {
        int row = node0 + m16;
        if (row >= n_nodes) row = n_nodes - 1;
        const float* hr = h + (size_t)row * HID + quad * 8;
#pragma unroll
        for (int kc = 0; kc < 4; ++kc) {
            float4 x0 = *(const float4*)(hr + kc * 32);
            float4 x1 = *(const float4*)(hr + kc * 32 + 4);
            short8 v;
            v[0] = f2bf(x0.x); v[1] = f2bf(x0.y); v[2] = f2bf(x0.z); v[3] = f2bf(x0.w);
            v[4] = f2bf(x1.x); v[5] = f2bf(x1.y); v[6] = f2bf(x1.z); v[7] = f2bf(x1.w);
            a1[kc] = v;
        }
    }

    // agg for this lane's 4 C-rows: sum the 4 reduced groups, scale by 1/100
    float4 a4;
    {
        float4 s = make_float4(0.f, 0.f, 0.f, 0.f);
#pragma unroll
        for (int g = 0; g < NGRP; ++g) {
            float4 p = *(const float4*)(agg4 + (size_t)g * NODE_PAD + node0 + quad * 4);
            s.x += p.x; s.y += p.y; s.z += p.z; s.w += p.w;
        }
        a4.x = s.x * 0.01f; a4.y = s.y * 0.01f; a4.z = s.z * 0.01f; a4.w = s.w * 0.01f;
    }

    // ---- staging thread mapping: kg = k-block of 8 rows, cc = n-block of 4
    const int kg = tid >> 5;     // 0..15
    const int cc = tid & 31;     // 0..31

    // ---- stage W1 -> LDS (fp32 read, transpose + bf16 convert in regs)
    {
        const float* src = W1 + (size_t)(kg * 8) * HID + cc * 4;
        float r[8][4];
#pragma unroll
        for (int j = 0; j < 8; ++j)
            *(float4*)r[j] = *(const float4*)(src + j * HID);
#pragma unroll
        for (int jj = 0; jj < 4; ++jj) {
            short8 v;
#pragma unroll
            for (int j = 0; j < 8; ++j) v[j] = f2bf(r[j][jj]);
            *(short8*)(WL + (cc * 4 + jj) * 136 + kg * 8) = v;
        }
    }
    __syncthreads();

    // ---- layer 1: 8 col-tiles of 16, K=128 in 4 MFMA steps each
#pragma unroll
    for (int nt = 0; nt < 8; ++nt) {
        floatx4 acc = {0.f, 0.f, 0.f, 0.f};
        const short* wb = WL + (nt * 16 + m16) * 136 + quad * 8;
#pragma unroll
        for (int kc = 0; kc < 4; ++kc) {
            short8 bfr = *(const short8*)(wb + kc * 32);
            acc = __builtin_amdgcn_mfma_f32_16x16x32_bf16(a1[kc], bfr, acc, 0, 0, 0);
        }
        int col = nt * 16 + m16;
        float bias = b1[col];
        float wagg = W1[(size_t)HID * HID + col];   // W1 row 128 (agg weight)
        float av[4] = {a4.x, a4.y, a4.z, a4.w};
#pragma unroll
        for (int r = 0; r < 4; ++r) {
            float v = acc[r] + bias + av[r] * wagg;
            float sg = __builtin_amdgcn_rcpf(1.0f + __expf(-v));
            v *= sg;                       // silu
            t_lds[wv][(quad * 4 + r) * 136 + col] = f2bf(v);
        }
    }

    __syncthreads();   // all waves done reading W1 before overwrite

    // ---- stage W2 into the SAME LDS buffer (fp32, transpose+convert)
    {
        const float* src = W2 + (size_t)(kg * 8) * HID + cc * 4;
        float r[8][4];
#pragma unroll
        for (int j = 0; j < 8; ++j)
            *(float4*)r[j] = *(const float4*)(src + j * HID);
#pragma unroll
        for (int jj = 0; jj < 4; ++jj) {
            short8 v;
#pragma unroll
            for (int j = 0; j < 8; ++j) v[j] = f2bf(r[j][jj]);
            *(short8*)(WL + (cc * 4 + jj) * 136 + kg * 8) = v;
        }
    }
    __syncthreads();

    // ---- A fragments for layer 2 from own LDS slice (A-layout, 16B aligned)
    short8 a2[4];
#pragma unroll
    for (int kc = 0; kc < 4; ++kc)
        a2[kc] = *(const short8*)(&t_lds[wv][m16 * 136 + kc * 32 + quad * 8]);

    // per-lane b2 in C-layout columns (write side of the scratch transpose)
    float b2v[8];
#pragma unroll
    for (int nt = 0; nt < 8; ++nt) b2v[nt] = b2[nt * 16 + m16];

    // ---- layer 2 + residual epilogue via wave-private LDS transpose.
    // t slice is consumed (a2 read above); per-wave DS ops execute in order,
    // so no barrier is needed between t reads / scratch writes / reads.
    float* scratch = (float*)&t_lds[wv][0];   // 16 rows x 17 fp32 (1088 B)
    const int erow = lane & 15;               // row handled on the read side
    const int ecg  = lane >> 4;               // 4-col group on the read side
#pragma unroll
    for (int nt = 0; nt < 8; ++nt) {
        floatx4 acc = {0.f, 0.f, 0.f, 0.f};
        const short* wb = WL + (nt * 16 + m16) * 136 + quad * 8;
#pragma unroll
        for (int kc = 0; kc < 4; ++kc) {
            short8 bfr = *(const short8*)(wb + kc * 32);
            acc = __builtin_amdgcn_mfma_f32_16x16x32_bf16(a2[kc], bfr, acc, 0, 0, 0);
        }
        // C-layout (col=m16, row=quad*4+r) -> scratch, bias fused
#pragma unroll
        for (int r = 0; r < 4; ++r)
            scratch[(quad * 4 + r) * 17 + m16] = acc[r] + b2v[nt];
        // transposed read + residual + coalesced float4 store
        float4 sv = *(const float4*)(scratch + erow * 17 + ecg * 4);
        int row = node0 + erow;
        if (row < n_nodes) {
            size_t off = (size_t)row * HID + nt * 16 + ecg * 4;
            float4 hv = *(const float4*)(h + off);
            float4 o = make_float4(hv.x + sv.x, hv.y + sv.y,
                                   hv.z + sv.z, hv.w + sv.w);
            *(float4*)(out + off) = o;
        }
    }
}

// ---------------------------------------------------------------------------
// Launch.  Inputs (setup_inputs order):
//  0 h[50000*128] f32 | 1 edges[2*800000] i32 | 2 distances[800000] f32
//  3..8 edge-MLP weights (DEAD CODE, unused)
//  9 W_n1[129*128] | 10 b_n1[128] | 11 W_n2[128*128] | 12 b_n2[128]
// d_ws: part bf16[NPART][NODE_PAD] (6.4 MB) | agg4 f32[NGRP][NODE_PAD]
//       (0.8 MB).  No zeroing needed: every element is overwritten.
// ---------------------------------------------------------------------------
extern "C" void kernel_launch(void* const* d_in, const int* in_sizes, int n_in,
                              void* d_out, int out_size, void* d_ws, size_t ws_size,
                              hipStream_t stream) {
    const float* h     = (const float*)d_in[0];
    const int*   edges = (const int*)d_in[1];
    const float* dist  = (const float*)d_in[2];
    const float* W1    = (const float*)d_in[9];
    const float* b1    = (const float*)d_in[10];
    const float* W2    = (const float*)d_in[11];
    const float* b2    = (const float*)d_in[12];
    float* out = (float*)d_out;

    const int n_nodes = in_sizes[0] / HID;
    const int n_edges = in_sizes[2];
    const int* rows = edges;   // edges[0, :]

    unsigned short* part = (unsigned short*)d_ws;
    float* agg4 = (float*)(part + (size_t)NPART * NODE_PAD);

    scatter_lds<<<NRANGE * NPART, 256, 0, stream>>>(rows, dist, part, n_edges);

    reduce_partials<<<NGRP * ((NODE_PAD / 8 + 255) / 256), 256, 0, stream>>>(part, agg4);

    const int blocks = (n_nodes + 127) / 128;
    node_mlp_mfma<<<blocks, 512, 0, stream>>>(h, agg4, W1, b1, W2, b2, out, n_nodes);
}